// Round 12
// baseline (1248.289 us; speedup 1.0000x reference)
//
#include <hip/hip_runtime.h>

// TAMCaD_T fused attention-over-variables.
// q,k,v: (B=16, G=32, H=32, S=4096) fp32, s contiguous.
// Per (b,s): logits[g][f] = scale * sum_d q[g,d]k[f,d]; attn = softmax_f; x[g,d] = sum_f attn*v[f,d].
// Outputs (concat fp32): x (B,G*H,S) | attentions (B,G,G,S) | logits (B,G,G,S).
//
// Round-8 structure (5th submit; repeated infra failures, kernel never executed):
//  - Staging + QK + softmax identical to round 2 (LDS-staged bf16 k/v, TS=16).
//  - attn redistribution is INTRA-WAVE: wave gt computes attn[g in gt*4..][all f]
//    and PV for those same g needs exactly that -> per-wave 2-KB double-buffered
//    LDS slice, written+read by the same wave (DS ops in-order), NO barrier.
//  - Exactly ONE __syncthreads (after k/v staging). k_lds/v_lds read-only after.
//    Waves drift freely; next block's staging overlaps this block's PV.
//  - LDS 32+32+16 = 80 KB -> 2 blocks/CU; launch_bounds(512,4) caps VGPR 128.

constexpr int S_LEN = 4096;
constexpr int GG = 32;   // groups (q and kv)
constexpr int HH = 32;   // hidden dim (dk), n_heads = 1
constexpr int TS = 16;   // timesteps per block -> 64-B global segments
constexpr float SCALE = 0.17677669529663687f;  // 32^-0.5

__device__ __forceinline__ unsigned bf16pack(float a, float b) {
    // round-to-nearest-even bf16 pair in a u32 (lo = a, hi = b)
    unsigned ua = __float_as_uint(a);
    unsigned ub = __float_as_uint(b);
    ua = (ua + 0x7fffu + ((ua >> 16) & 1u)) >> 16;
    ub = (ub + 0x7fffu + ((ub >> 16) & 1u)) >> 16;
    return ua | (ub << 16);
}

__global__ __launch_bounds__(512, 4) void tamcad_fused(
    const float* __restrict__ q, const float* __restrict__ k,
    const float* __restrict__ v, float* __restrict__ x_out,
    float* __restrict__ attn_out, float* __restrict__ logit_out)
{
    // k/v: bf16 s-pairs, u32 word for (row, sp) at row*8 + (sp ^ (row&4)).
    // k rows rotated (d + f>>2)&31; v rows bit-rotated ((d&3)<<3)|(d>>2).
    __shared__ __align__(16) unsigned k_lds[GG * HH * TS / 2];  // 8192 u32 = 32 KB
    __shared__ __align__(16) unsigned v_lds[GG * HH * TS / 2];  // 32 KB
    // per-wave attn transpose scratch: 8 waves x 512 u32 (two 256-u32 slots) = 16 KB
    __shared__ __align__(16) unsigned a_lds[8 * 512];

    // XCD-bijective swizzle (nwg = 4096, divisible by 8)
    const int nwg = gridDim.x;
    const int cpx = nwg >> 3;
    const int raw = blockIdx.x;
    const int logical = (raw & 7) * cpx + (raw >> 3);
    const int b  = logical >> 8;       // / (S/TS = 256)
    const int st = logical & 255;
    const int s0 = st * TS;

    const int tid = threadIdx.x;
    const int gt = tid >> 6;           // 0..7  g-tile (one per wave)
    const int ft = (tid >> 3) & 7;     // 0..7  f-tile (QK) / d-tile (PV)
    const int sp = tid & 7;            // 0..7  s-pair (2 timesteps each)

    const int baseB = b * (GG * HH);   // row base (rows of length S)
    const float* qb = q + (size_t)baseB * S_LEN + s0;
    const float* kb = k + (size_t)baseB * S_LEN + s0;
    const float* vb = v + (size_t)baseB * S_LEN + s0;

    // ---------------- stage k, v -> LDS bf16 (swizzled; round-2 layout) ----------------
    for (int r = tid; r < GG * HH; r += 512) {
        const int f = r >> 5, d = r & 31;
        const float4* ks = reinterpret_cast<const float4*>(kb + (size_t)r * S_LEN);
        const float4* vs = reinterpret_cast<const float4*>(vb + (size_t)r * S_LEN);
        float4 k0 = ks[0], k1 = ks[1], k2 = ks[2], k3 = ks[3];
        float4 v0 = vs[0], v1 = vs[1], v2 = vs[2], v3 = vs[3];
        uint4 kl, kh, vl, vh;
        kl.x = bf16pack(k0.x, k0.y); kl.y = bf16pack(k0.z, k0.w);
        kl.z = bf16pack(k1.x, k1.y); kl.w = bf16pack(k1.z, k1.w);
        kh.x = bf16pack(k2.x, k2.y); kh.y = bf16pack(k2.z, k2.w);
        kh.z = bf16pack(k3.x, k3.y); kh.w = bf16pack(k3.z, k3.w);
        vl.x = bf16pack(v0.x, v0.y); vl.y = bf16pack(v0.z, v0.w);
        vl.z = bf16pack(v1.x, v1.y); vl.w = bf16pack(v1.z, v1.w);
        vh.x = bf16pack(v2.x, v2.y); vh.y = bf16pack(v2.z, v2.w);
        vh.z = bf16pack(v3.x, v3.y); vh.w = bf16pack(v3.z, v3.w);
        const int rk = f * 32 + ((d + (f >> 2)) & 31);
        const int xk = rk & 4;
        *reinterpret_cast<uint4*>(&k_lds[rk * 8 + xk])       = kl;  // sp 0-3
        *reinterpret_cast<uint4*>(&k_lds[rk * 8 + (4 ^ xk)]) = kh;  // sp 4-7
        const int rv = f * 32 + (((d & 3) << 3) | (d >> 2));
        const int xv = rv & 4;
        *reinterpret_cast<uint4*>(&v_lds[rv * 8 + xv])       = vl;
        *reinterpret_cast<uint4*>(&v_lds[rv * 8 + (4 ^ xv)]) = vh;
    }
    __syncthreads();   // the ONLY barrier; k_lds/v_lds read-only from here

    // ---------------- QK^T: acc[4g][4f][2s] ----------------
    float acc[4][4][2];
    #pragma unroll
    for (int j = 0; j < 4; ++j)
        #pragma unroll
        for (int i = 0; i < 4; ++i) { acc[j][i][0] = 0.f; acc[j][i][1] = 0.f; }

    {
        const float* qrow[4];
        #pragma unroll
        for (int j = 0; j < 4; ++j)
            qrow[j] = qb + (size_t)((gt * 4 + j) * HH) * S_LEN + sp * 2;

        #pragma unroll 4
        for (int d = 0; d < HH; ++d) {
            float2 qv[4];
            #pragma unroll
            for (int j = 0; j < 4; ++j)
                qv[j] = *reinterpret_cast<const float2*>(qrow[j] + (size_t)d * S_LEN);
            const int dd = (d + ft) & 31;        // store rotation (f>>2 == ft)
            const int so = sp ^ (dd & 4);
            #pragma unroll
            for (int i = 0; i < 4; ++i) {
                const unsigned w = k_lds[((ft * 4 + i) * 32 + dd) * 8 + so];
                const float klo = __uint_as_float(w << 16);
                const float khi = __uint_as_float(w & 0xffff0000u);
                #pragma unroll
                for (int j = 0; j < 4; ++j) {
                    acc[j][i][0] = fmaf(qv[j].x, klo, acc[j][i][0]);
                    acc[j][i][1] = fmaf(qv[j].y, khi, acc[j][i][1]);
                }
            }
        }
    }
    #pragma unroll
    for (int j = 0; j < 4; ++j)
        #pragma unroll
        for (int i = 0; i < 4; ++i) { acc[j][i][0] *= SCALE; acc[j][i][1] *= SCALE; }

    // ---------------- softmax over f (4 local f x 8 ft lanes; intra-wave) ----------------
    float mx[4][2];
    #pragma unroll
    for (int j = 0; j < 4; ++j) {
        #pragma unroll
        for (int e = 0; e < 2; ++e) {
            float m = fmaxf(fmaxf(acc[j][0][e], acc[j][1][e]),
                            fmaxf(acc[j][2][e], acc[j][3][e]));
            m = fmaxf(m, __shfl_xor(m, 8));
            m = fmaxf(m, __shfl_xor(m, 16));
            m = fmaxf(m, __shfl_xor(m, 32));
            mx[j][e] = m;
        }
    }
    // store logits, overwrite acc in place with exp(acc - m)
    #pragma unroll
    for (int j = 0; j < 4; ++j) {
        const int g = gt * 4 + j;
        #pragma unroll
        for (int i = 0; i < 4; ++i) {
            const int f = ft * 4 + i;
            const size_t o = (size_t)(baseB + g * GG + f) * S_LEN + s0 + sp * 2;
            *reinterpret_cast<float2*>(logit_out + o) = make_float2(acc[j][i][0], acc[j][i][1]);
            acc[j][i][0] = __expf(acc[j][i][0] - mx[j][0]);
            acc[j][i][1] = __expf(acc[j][i][1] - mx[j][1]);
        }
    }
    float inv[4][2];
    #pragma unroll
    for (int j = 0; j < 4; ++j) {
        #pragma unroll
        for (int e = 0; e < 2; ++e) {
            float s = acc[j][0][e] + acc[j][1][e] + acc[j][2][e] + acc[j][3][e];
            s += __shfl_xor(s, 8);
            s += __shfl_xor(s, 16);
            s += __shfl_xor(s, 32);
            inv[j][e] = __builtin_amdgcn_rcpf(s);
        }
    }
    // attn: global store + bf16 pack (apack[i][j]; chunk i holds f = 4*ft + i)
    unsigned apack[4][4];
    #pragma unroll
    for (int j = 0; j < 4; ++j) {
        const int g = gt * 4 + j;
        #pragma unroll
        for (int i = 0; i < 4; ++i) {
            const int f = ft * 4 + i;
            const float a0 = acc[j][i][0] * inv[j][0];
            const float a1 = acc[j][i][1] * inv[j][1];
            const size_t o = (size_t)(baseB + g * GG + f) * S_LEN + s0 + sp * 2;
            *reinterpret_cast<float2*>(attn_out + o) = make_float2(a0, a1);
            apack[i][j] = bf16pack(a0, a1);
        }
    }

    // ---------------- PV via per-wave chunked transpose (NO barrier) ----------------
    // chunk fc = {f : f mod 4 == fc}; slot (fc&1) of this wave's 512-u32 slice.
    // write: lane (ft,sp) -> uint4 at (ft*8+sp)*4 (contiguous b128, conflict-free).
    // read:  slot[(t*8+sp)*4] -> f = 4t+fc; broadcast over dt, 32-bank over sp.
    unsigned* const slice = &a_lds[gt * 512];
    const int wsl = (ft * 8 + sp) * 4;
    {
        uint4 w;
        w.x = apack[0][0]; w.y = apack[0][1]; w.z = apack[0][2]; w.w = apack[0][3];
        *reinterpret_cast<uint4*>(&slice[wsl]) = w;   // chunk 0 -> slot 0
    }

    float xacc[4][4][2];
    #pragma unroll
    for (int j = 0; j < 4; ++j)
        #pragma unroll
        for (int i = 0; i < 4; ++i) { xacc[j][i][0] = 0.f; xacc[j][i][1] = 0.f; }

    const int dt = ft;
    const int sov = sp ^ (dt & 4);   // v-row XOR: rv&4 == dt&4
    #pragma unroll
    for (int fc = 0; fc < 4; ++fc) {
        // write next chunk into the other slot (issued before this chunk's math;
        // same-wave DS ops are in-order, so no hazard with slot (fc&1) reads)
        if (fc < 3) {
            uint4 w;
            w.x = apack[fc + 1][0]; w.y = apack[fc + 1][1];
            w.z = apack[fc + 1][2]; w.w = apack[fc + 1][3];
            *reinterpret_cast<uint4*>(&slice[((fc + 1) & 1) * 256 + wsl]) = w;
        }
        #pragma unroll
        for (int t = 0; t < 8; ++t) {
            const int f = t * 4 + fc;
            const uint4 wa = *reinterpret_cast<const uint4*>(
                &slice[(fc & 1) * 256 + (t * 8 + sp) * 4]);
            float alo[4], ahi[4];
            alo[0] = __uint_as_float(wa.x << 16); ahi[0] = __uint_as_float(wa.x & 0xffff0000u);
            alo[1] = __uint_as_float(wa.y << 16); ahi[1] = __uint_as_float(wa.y & 0xffff0000u);
            alo[2] = __uint_as_float(wa.z << 16); ahi[2] = __uint_as_float(wa.z & 0xffff0000u);
            alo[3] = __uint_as_float(wa.w << 16); ahi[3] = __uint_as_float(wa.w & 0xffff0000u);
            #pragma unroll
            for (int i = 0; i < 4; ++i) {
                // d = dt*4+i stored at pi(d) = i*8 + dt
                const unsigned wv = v_lds[(f * 32 + i * 8 + dt) * 8 + sov];
                const float vlo = __uint_as_float(wv << 16);
                const float vhi = __uint_as_float(wv & 0xffff0000u);
                #pragma unroll
                for (int j = 0; j < 4; ++j) {
                    xacc[j][i][0] = fmaf(alo[j], vlo, xacc[j][i][0]);
                    xacc[j][i][1] = fmaf(ahi[j], vhi, xacc[j][i][1]);
                }
            }
        }
    }
    // store x: x[b, g*32+d, s]
    #pragma unroll
    for (int j = 0; j < 4; ++j) {
        const int g = gt * 4 + j;
        #pragma unroll
        for (int i = 0; i < 4; ++i) {
            const int d = dt * 4 + i;
            const size_t o = (size_t)(baseB + g * HH + d) * S_LEN + s0 + sp * 2;
            *reinterpret_cast<float2*>(x_out + o) = make_float2(xacc[j][i][0], xacc[j][i][1]);
        }
    }
}

extern "C" void kernel_launch(void* const* d_in, const int* in_sizes, int n_in,
                              void* d_out, int out_size, void* d_ws, size_t ws_size,
                              hipStream_t stream) {
    const float* q = (const float*)d_in[0];
    const float* k = (const float*)d_in[1];
    const float* v = (const float*)d_in[2];
    float* out = (float*)d_out;
    const int n = in_sizes[0];                  // B*G*H*S = 67108864
    const int B = n / (GG * HH * S_LEN);        // 16
    float* x_out     = out;
    float* attn_out  = out + (size_t)n;
    float* logit_out = out + (size_t)2 * n;
    const int nwg = B * (S_LEN / TS);           // 4096
    tamcad_fused<<<dim3(nwg), dim3(512), 0, stream>>>(q, k, v, x_out, attn_out, logit_out);
}

// Round 13
// 671.516 us; speedup vs baseline: 1.8589x; 1.8589x over previous
//
#include <hip/hip_runtime.h>

// TAMCaD_T fused attention-over-variables — TWO-KERNEL SPLIT.
// q,k,v: (B=16, G=32, H=32, S=4096) fp32, s contiguous.
// Per (b,s): logits[g][f] = scale * sum_d q[g,d]k[f,d]; attn = softmax_f; x[g,d] = sum_f attn*v[f,d].
// Outputs (concat fp32): x (B,G*H,S) | attentions (B,G,G,S) | logits (B,G,G,S).
//
// Round-13: rounds 3/6/12 all prove hipcc allocates ~64 VGPR here and spills
// anything fatter (round 12: +2.6 GB spill traffic, 1248 us). Round 2 (56 VGPR,
// 513 us) is the no-spill shape. So: split QK and PV into separate kernels,
// each with round-2's register profile (~56), 32 KB LDS (4 blocks/CU, 2x round 2),
// ONE barrier each, no mid-kernel phase serialization.
//  - A (tamcad_qk): stage k bf16 -> QK (q streamed) -> softmax -> logits+attn.
//  - B (tamcad_pv): stage v bf16 -> PV (attn streamed fp32 from attn_out) -> x.
// Stream order serializes A before B. Extra cost: attn re-read 256 MB (+17%).

constexpr int S_LEN = 4096;
constexpr int GG = 32;   // groups (q and kv)
constexpr int HH = 32;   // hidden dim (dk), n_heads = 1
constexpr int TS = 16;   // timesteps per block -> 64-B global segments
constexpr float SCALE = 0.17677669529663687f;  // 32^-0.5

__device__ __forceinline__ unsigned bf16pack(float a, float b) {
    // round-to-nearest-even bf16 pair in a u32 (lo = a, hi = b)
    unsigned ua = __float_as_uint(a);
    unsigned ub = __float_as_uint(b);
    ua = (ua + 0x7fffu + ((ua >> 16) & 1u)) >> 16;
    ub = (ub + 0x7fffu + ((ub >> 16) & 1u)) >> 16;
    return ua | (ub << 16);
}

__device__ __forceinline__ int xcd_block(int raw, int nwg) {
    // XCD-bijective swizzle (nwg divisible by 8)
    return (raw & 7) * (nwg >> 3) + (raw >> 3);
}

// ================= Kernel A: logits + attn =================
__global__ __launch_bounds__(512, 4) void tamcad_qk(
    const float* __restrict__ q, const float* __restrict__ k,
    float* __restrict__ attn_out, float* __restrict__ logit_out)
{
    // k tile: bf16 s-pairs, u32 word for (row, sp) at row*8 + (sp ^ (row&4));
    // rows rotated: rk = f*32 + ((d + f>>2) & 31).
    __shared__ __align__(16) unsigned k_lds[GG * HH * TS / 2];  // 8192 u32 = 32 KB

    const int logical = xcd_block(blockIdx.x, gridDim.x);
    const int b  = logical >> 8;       // / (S/TS = 256)
    const int st = logical & 255;
    const int s0 = st * TS;

    const int tid = threadIdx.x;
    const int gt = tid >> 6;           // 0..7  g-tile (one per wave)
    const int ft = (tid >> 3) & 7;     // 0..7  f-tile
    const int sp = tid & 7;            // 0..7  s-pair (2 timesteps)

    const int baseB = b * (GG * HH);
    const float* qb = q + (size_t)baseB * S_LEN + s0;
    const float* kb = k + (size_t)baseB * S_LEN + s0;

    // ---- stage k -> LDS bf16 (2 rows/thread) ----
    for (int r = tid; r < GG * HH; r += 512) {
        const int f = r >> 5, d = r & 31;
        const float4* ks = reinterpret_cast<const float4*>(kb + (size_t)r * S_LEN);
        float4 k0 = ks[0], k1 = ks[1], k2 = ks[2], k3 = ks[3];
        uint4 kl, kh;
        kl.x = bf16pack(k0.x, k0.y); kl.y = bf16pack(k0.z, k0.w);
        kl.z = bf16pack(k1.x, k1.y); kl.w = bf16pack(k1.z, k1.w);
        kh.x = bf16pack(k2.x, k2.y); kh.y = bf16pack(k2.z, k2.w);
        kh.z = bf16pack(k3.x, k3.y); kh.w = bf16pack(k3.z, k3.w);
        const int rk = f * 32 + ((d + (f >> 2)) & 31);
        const int xk = rk & 4;
        *reinterpret_cast<uint4*>(&k_lds[rk * 8 + xk])       = kl;  // sp 0-3
        *reinterpret_cast<uint4*>(&k_lds[rk * 8 + (4 ^ xk)]) = kh;  // sp 4-7
    }
    __syncthreads();   // the only barrier

    // ---- QK^T: acc[4g][4f][2s] ----
    float acc[4][4][2];
    #pragma unroll
    for (int j = 0; j < 4; ++j)
        #pragma unroll
        for (int i = 0; i < 4; ++i) { acc[j][i][0] = 0.f; acc[j][i][1] = 0.f; }

    {
        const float* qrow[4];
        #pragma unroll
        for (int j = 0; j < 4; ++j)
            qrow[j] = qb + (size_t)((gt * 4 + j) * HH) * S_LEN + sp * 2;

        #pragma unroll 4
        for (int d = 0; d < HH; ++d) {
            float2 qv[4];
            #pragma unroll
            for (int j = 0; j < 4; ++j)
                qv[j] = *reinterpret_cast<const float2*>(qrow[j] + (size_t)d * S_LEN);
            const int dd = (d + ft) & 31;        // matches store rotation (f>>2 == ft)
            const int so = sp ^ (dd & 4);
            #pragma unroll
            for (int i = 0; i < 4; ++i) {
                const unsigned w = k_lds[((ft * 4 + i) * 32 + dd) * 8 + so];
                const float klo = __uint_as_float(w << 16);
                const float khi = __uint_as_float(w & 0xffff0000u);
                #pragma unroll
                for (int j = 0; j < 4; ++j) {
                    acc[j][i][0] = fmaf(qv[j].x, klo, acc[j][i][0]);
                    acc[j][i][1] = fmaf(qv[j].y, khi, acc[j][i][1]);
                }
            }
        }
    }
    #pragma unroll
    for (int j = 0; j < 4; ++j)
        #pragma unroll
        for (int i = 0; i < 4; ++i) { acc[j][i][0] *= SCALE; acc[j][i][1] *= SCALE; }

    // ---- softmax over f (4 local f x 8 ft lanes) ----
    float mx[4][2];
    #pragma unroll
    for (int j = 0; j < 4; ++j) {
        #pragma unroll
        for (int e = 0; e < 2; ++e) {
            float m = fmaxf(fmaxf(acc[j][0][e], acc[j][1][e]),
                            fmaxf(acc[j][2][e], acc[j][3][e]));
            m = fmaxf(m, __shfl_xor(m, 8));
            m = fmaxf(m, __shfl_xor(m, 16));
            m = fmaxf(m, __shfl_xor(m, 32));
            mx[j][e] = m;
        }
    }
    // store logits, overwrite acc with exp(acc - m)
    #pragma unroll
    for (int j = 0; j < 4; ++j) {
        const int g = gt * 4 + j;
        #pragma unroll
        for (int i = 0; i < 4; ++i) {
            const int f = ft * 4 + i;
            const size_t o = (size_t)(baseB + g * GG + f) * S_LEN + s0 + sp * 2;
            *reinterpret_cast<float2*>(logit_out + o) = make_float2(acc[j][i][0], acc[j][i][1]);
            acc[j][i][0] = __expf(acc[j][i][0] - mx[j][0]);
            acc[j][i][1] = __expf(acc[j][i][1] - mx[j][1]);
        }
    }
    float inv[4][2];
    #pragma unroll
    for (int j = 0; j < 4; ++j) {
        #pragma unroll
        for (int e = 0; e < 2; ++e) {
            float s = acc[j][0][e] + acc[j][1][e] + acc[j][2][e] + acc[j][3][e];
            s += __shfl_xor(s, 8);
            s += __shfl_xor(s, 16);
            s += __shfl_xor(s, 32);
            inv[j][e] = __builtin_amdgcn_rcpf(s);
        }
    }
    #pragma unroll
    for (int j = 0; j < 4; ++j) {
        const int g = gt * 4 + j;
        #pragma unroll
        for (int i = 0; i < 4; ++i) {
            const int f = ft * 4 + i;
            const size_t o = (size_t)(baseB + g * GG + f) * S_LEN + s0 + sp * 2;
            *reinterpret_cast<float2*>(attn_out + o) =
                make_float2(acc[j][i][0] * inv[j][0], acc[j][i][1] * inv[j][1]);
        }
    }
}

// ================= Kernel B: x = attn @ v =================
__global__ __launch_bounds__(512, 4) void tamcad_pv(
    const float* __restrict__ v, const float* __restrict__ attn_in,
    float* __restrict__ x_out)
{
    // v tile: bf16 s-pairs, word (row, sp) at row*8 + (sp ^ (row&4));
    // rows bit-rotated: rv = f*32 + (((d&3)<<3)|(d>>2)).
    __shared__ __align__(16) unsigned v_lds[GG * HH * TS / 2];  // 32 KB

    const int logical = xcd_block(blockIdx.x, gridDim.x);
    const int b  = logical >> 8;
    const int st = logical & 255;
    const int s0 = st * TS;

    const int tid = threadIdx.x;
    const int gt = tid >> 6;           // 0..7  g-tile
    const int dt = (tid >> 3) & 7;     // 0..7  d-tile
    const int sp = tid & 7;            // 0..7  s-pair

    const int baseB = b * (GG * HH);
    const float* vb = v + (size_t)baseB * S_LEN + s0;

    // ---- stage v -> LDS bf16 (2 rows/thread) ----
    for (int r = tid; r < GG * HH; r += 512) {
        const int f = r >> 5, d = r & 31;
        const float4* vs = reinterpret_cast<const float4*>(vb + (size_t)r * S_LEN);
        float4 v0 = vs[0], v1 = vs[1], v2 = vs[2], v3 = vs[3];
        uint4 vl, vh;
        vl.x = bf16pack(v0.x, v0.y); vl.y = bf16pack(v0.z, v0.w);
        vl.z = bf16pack(v1.x, v1.y); vl.w = bf16pack(v1.z, v1.w);
        vh.x = bf16pack(v2.x, v2.y); vh.y = bf16pack(v2.z, v2.w);
        vh.z = bf16pack(v3.x, v3.y); vh.w = bf16pack(v3.z, v3.w);
        const int rv = f * 32 + (((d & 3) << 3) | (d >> 2));
        const int xv = rv & 4;
        *reinterpret_cast<uint4*>(&v_lds[rv * 8 + xv])       = vl;
        *reinterpret_cast<uint4*>(&v_lds[rv * 8 + (4 ^ xv)]) = vh;
    }
    __syncthreads();   // the only barrier

    // ---- PV: xacc[4g][4d][2s]; attn streamed fp32 from attn_in ----
    float xacc[4][4][2];
    #pragma unroll
    for (int j = 0; j < 4; ++j)
        #pragma unroll
        for (int i = 0; i < 4; ++i) { xacc[j][i][0] = 0.f; xacc[j][i][1] = 0.f; }

    {
        const float* arow[4];
        #pragma unroll
        for (int j = 0; j < 4; ++j)
            arow[j] = attn_in + (size_t)(baseB + (gt * 4 + j) * GG) * S_LEN + s0 + sp * 2;

        const int sov = sp ^ (dt & 4);   // rv&4 == dt&4 for rows f*32 + i*8 + dt
        #pragma unroll 4
        for (int f = 0; f < GG; ++f) {
            float2 av[4];
            #pragma unroll
            for (int j = 0; j < 4; ++j)
                av[j] = *reinterpret_cast<const float2*>(arow[j] + (size_t)f * S_LEN);
            #pragma unroll
            for (int i = 0; i < 4; ++i) {
                // d = dt*4+i stored at pi(d) = i*8 + dt
                const unsigned wv = v_lds[(f * 32 + i * 8 + dt) * 8 + sov];
                const float vlo = __uint_as_float(wv << 16);
                const float vhi = __uint_as_float(wv & 0xffff0000u);
                #pragma unroll
                for (int j = 0; j < 4; ++j) {
                    xacc[j][i][0] = fmaf(av[j].x, vlo, xacc[j][i][0]);
                    xacc[j][i][1] = fmaf(av[j].y, vhi, xacc[j][i][1]);
                }
            }
        }
    }
    // store x: x[b, g*32+d, s]
    #pragma unroll
    for (int j = 0; j < 4; ++j) {
        const int g = gt * 4 + j;
        #pragma unroll
        for (int i = 0; i < 4; ++i) {
            const int d = dt * 4 + i;
            const size_t o = (size_t)(baseB + g * HH + d) * S_LEN + s0 + sp * 2;
            *reinterpret_cast<float2*>(x_out + o) = make_float2(xacc[j][i][0], xacc[j][i][1]);
        }
    }
}

extern "C" void kernel_launch(void* const* d_in, const int* in_sizes, int n_in,
                              void* d_out, int out_size, void* d_ws, size_t ws_size,
                              hipStream_t stream) {
    const float* q = (const float*)d_in[0];
    const float* k = (const float*)d_in[1];
    const float* v = (const float*)d_in[2];
    float* out = (float*)d_out;
    const int n = in_sizes[0];                  // B*G*H*S = 67108864
    const int B = n / (GG * HH * S_LEN);        // 16
    float* x_out     = out;
    float* attn_out  = out + (size_t)n;
    float* logit_out = out + (size_t)2 * n;
    const int nwg = B * (S_LEN / TS);           // 4096
    tamcad_qk<<<dim3(nwg), dim3(512), 0, stream>>>(q, k, attn_out, logit_out);
    tamcad_pv<<<dim3(nwg), dim3(512), 0, stream>>>(v, attn_out, x_out);
}